// Round 13
// baseline (313.019 us; speedup 1.0000x reference)
//
#include <hip/hip_runtime.h>
#include <hip/hip_bf16.h>
#include <stdint.h>

#define DI __device__ __forceinline__

typedef __bf16 bf16x4 __attribute__((ext_vector_type(4)));
typedef __bf16 bf16x8 __attribute__((ext_vector_type(8)));
typedef float  f32x4  __attribute__((ext_vector_type(4)));

static constexpr int  BATCH = 4;
static constexpr int  SEQ   = 4096;
static constexpr int  DIM   = 768;
static constexpr long TOK   = (long)BATCH * SEQ;        // 16384
static constexpr int  QT    = SEQ / 128;                // 32 q-tiles per batch
static constexpr int  NTRI  = QT * (QT + 1) / 2;        // 528 causal 128x128 tiles
static constexpr float SCALE = 0.0360843918243516150f;  // 1/sqrt(768)

// ---------------- fp32 -> bf16 convert (all 7 tensors, one dispatch) ----------
__global__ void cvt_all(const float* __restrict__ a0, const float* __restrict__ a1,
                        const float* __restrict__ a2, const float* __restrict__ a3,
                        const float* __restrict__ a4, const float* __restrict__ a5,
                        const float* __restrict__ a6,
                        __bf16* __restrict__ o0, __bf16* __restrict__ o1,
                        __bf16* __restrict__ o2, __bf16* __restrict__ o3,
                        __bf16* __restrict__ o4, __bf16* __restrict__ o5,
                        __bf16* __restrict__ o6, long n4big, long n4w){
  const int y = blockIdx.y;
  const float* in; __bf16* out; long n4;
  switch(y){
    case 0: in = a0; out = o0; n4 = n4big; break;
    case 1: in = a1; out = o1; n4 = n4big; break;
    case 2: in = a2; out = o2; n4 = n4big; break;
    case 3: in = a3; out = o3; n4 = n4w;   break;
    case 4: in = a4; out = o4; n4 = n4w;   break;
    case 5: in = a5; out = o5; n4 = n4w;   break;
    default: in = a6; out = o6; n4 = n4w;  break;
  }
  long i = (long)blockIdx.x * blockDim.x + threadIdx.x;
  const long stride = (long)gridDim.x * blockDim.x;
  for(; i < n4; i += stride){
    float4 v = ((const float4*)in)[i];
    bf16x4 o = { (__bf16)v.x, (__bf16)v.y, (__bf16)v.z, (__bf16)v.w };
    ((bf16x4*)out)[i] = o;
  }
}

// ================= proven 2-phase core (qk / pv / oproj) =================
// LDS tile: [R rows][64 bf16 = 8 chunks of 16B], chunk XOR-swizzled by (row&7).
DI int swz_off(int r, int c){ return (r << 7) + ((c ^ (r & 7)) << 4); }

template<int NT, int R>
DI void stage(const __bf16* __restrict__ src, long ld, char* lds, int tid){
  const int w = tid >> 6, l = tid & 63;
  const int rsub = l >> 3;
  const int kc   = (l & 7) ^ rsub;
  const __bf16* g = src + (long)(w * 8 + rsub) * ld + kc * 8;
  char* d = lds + (w << 10);
  constexpr int RPC = NT / 8;
  #pragma unroll
  for(int i = 0; i < R / RPC; ++i){
    __builtin_amdgcn_global_load_lds(
        (const __attribute__((address_space(1))) void*)(g + (long)(i * RPC) * ld),
        (__attribute__((address_space(3))) void*)(d + i * RPC * 128), 16, 0, 0);
  }
}

// triple bf16 source, summed (oproj A = att0 + att1 + att2), same layout.
template<int NT, int R>
DI void stage_add3(const __bf16* __restrict__ a0, const __bf16* __restrict__ a1,
                   const __bf16* __restrict__ a2, long ld, char* lds, int tid){
  const int w = tid >> 6, l = tid & 63;
  const int rsub = l >> 3;
  const int kc   = (l & 7) ^ rsub;
  const long off = (long)(w * 8 + rsub) * ld + kc * 8;
  char* d = lds + (w << 10) + (l << 4);
  constexpr int RPC = NT / 8;
  #pragma unroll
  for(int i = 0; i < R / RPC; ++i){
    bf16x8 v0 = *(const bf16x8*)(a0 + off + (long)(i * RPC) * ld);
    bf16x8 v1 = *(const bf16x8*)(a1 + off + (long)(i * RPC) * ld);
    bf16x8 v2 = *(const bf16x8*)(a2 + off + (long)(i * RPC) * ld);
    bf16x8 o;
    #pragma unroll
    for(int e = 0; e < 8; ++e)
      o[e] = (__bf16)((float)v0[e] + (float)v1[e] + (float)v2[e]);
    *(bf16x8*)(d + i * RPC * 128) = o;
  }
}

DI bf16x8 frag_ld(const char* lds, int row, int c){
  return *(const bf16x8*)(lds + swz_off(row, c));
}

// One K=64 step: 32 MFMAs per wave (4x4 frags x 2 k-halves).
DI void mma_tile(const char* As, const char* Bs, int lane, int wr, int wc, f32x4 acc[4][4]){
  #pragma unroll
  for(int kk = 0; kk < 2; ++kk){
    const int c = kk * 4 + (lane >> 4);
    bf16x8 a[4], b[4];
    #pragma unroll
    for(int i = 0; i < 4; ++i) a[i] = frag_ld(As, wr + i * 16 + (lane & 15), c);
    #pragma unroll
    for(int j = 0; j < 4; ++j) b[j] = frag_ld(Bs, wc + j * 16 + (lane & 15), c);
    #pragma unroll
    for(int i = 0; i < 4; ++i)
      #pragma unroll
      for(int j = 0; j < 4; ++j)
        acc[i][j] = __builtin_amdgcn_mfma_f32_16x16x32_bf16(a[i], b[j], acc[i][j], 0, 0, 0);
  }
}

// Single-buffered 128x256 K-loop (48KB LDS -> 3 blocks/CU), all-bf16 operands.
template<class FA, class FB>
DI void kloop2(FA fa, long lda, FB fb, long ldb, int nt, int tid,
               char* As, char* Bs, f32x4 acc[4][4]){
  const int lane = tid & 63, w = tid >> 6;
  const int wr = (w >> 2) * 64, wc = (w & 3) * 64;
  for(int t = 0; t < nt; ++t){
    stage<512, 128>(fa(t), lda, As, tid);
    stage<512, 256>(fb(t), ldb, Bs, tid);
    __syncthreads();
    mma_tile(As, Bs, lane, wr, wc, acc);
    __syncthreads();
  }
}

// ================= round-6-verified 256x256 8-phase core (proj) =================
DI void issue_unit(const __bf16* __restrict__ src, long ld, char* slab, int tid){
  const int w = tid >> 6, lane = tid & 63;
  #pragma unroll
  for(int r = 0; r < 2; ++r){
    const int row = w * 16 + (lane >> 2) + r * 128;
    const int c   = (lane & 3) ^ ((row >> 1) & 3);
    const __bf16* g = src + (long)row * ld + c * 8;
    __builtin_amdgcn_global_load_lds(
        (const __attribute__((address_space(1))) void*)g,
        (__attribute__((address_space(3))) void*)(slab + w * 1024 + r * 8192), 16, 0, 0);
  }
}

template<int G>
DI void mma16(f32x4 (&acc)[8][4], const bf16x8 (&a)[4], const bf16x8 (&b)[4]){
  __builtin_amdgcn_s_setprio(1);
  #pragma unroll
  for(int i = 0; i < 4; ++i)
    #pragma unroll
    for(int j = 0; j < 4; ++j)
      acc[G * 4 + i][j] =
          __builtin_amdgcn_mfma_f32_16x16x32_bf16(a[i], b[j], acc[G * 4 + i][j], 0, 0, 0);
  __builtin_amdgcn_s_setprio(0);
}
template<int G>
DI void rdA(bf16x8 (&a)[4], const char* LA, int sbase, const int (&offA)[8]){
  #pragma unroll
  for(int i = 0; i < 4; ++i) a[i] = *(const bf16x8*)(LA + sbase + offA[G * 4 + i]);
}
DI void rdB(bf16x8 (&b)[4], const char* LB, int sbase, const int (&offB)[4]){
  #pragma unroll
  for(int j = 0; j < 4; ++j) b[j] = *(const bf16x8*)(LB + sbase + offB[j]);
}
#define VMW(N) asm volatile("s_waitcnt vmcnt(" #N ")" ::: "memory")

template<class FA, class FB>
DI void kloop8(FA fa, long lda, FB fb, long ldb, int nt, int tid,
               char* L, f32x4 (&acc)[8][4]){
  const int lane = tid & 63, w = tid >> 6;
  int offA[8], offB[4];
  #pragma unroll
  for(int i = 0; i < 8; ++i){
    const int r = (w >> 2) * 128 + i * 16 + (lane & 15);
    offA[i] = r * 64 + ((((lane >> 4)) ^ ((r >> 1) & 3)) << 4);
  }
  #pragma unroll
  for(int j = 0; j < 4; ++j){
    const int r = (w & 3) * 64 + j * 16 + (lane & 15);
    offB[j] = r * 64 + ((((lane >> 4)) ^ ((r >> 1) & 3)) << 4);
  }
  char* LA = L;
  char* LB = L + 65536;
  auto AS = [](int s, int k){ return s * 32768 + k * 16384; };
  issue_unit(fa(0),      lda, LA + AS(0, 0), tid);
  issue_unit(fb(0),      ldb, LB + AS(0, 0), tid);
  issue_unit(fa(0) + 32, lda, LA + AS(0, 1), tid);
  issue_unit(fb(0) + 32, ldb, LB + AS(0, 1), tid);
  issue_unit(fa(1),      lda, LA + AS(1, 0), tid);
  issue_unit(fb(1),      ldb, LB + AS(1, 0), tid);
  bf16x8 a[4], b[4];
  for(int t = 0; t < nt; t += 2){
    const bool more = (t + 2 < nt);
    VMW(8); __builtin_amdgcn_s_barrier();                       // ph1
    issue_unit(fa(t + 1) + 32, lda, LA + AS(1, 1), tid);
    rdB(b, LB, AS(0, 0), offB);
    rdA<0>(a, LA, AS(0, 0), offA);  mma16<0>(acc, a, b);
    issue_unit(fb(t + 1) + 32, ldb, LB + AS(1, 1), tid);        // ph2
    rdA<1>(a, LA, AS(0, 0), offA);  mma16<1>(acc, a, b);
    VMW(8); __builtin_amdgcn_s_barrier();                       // ph3
    if(more) issue_unit(fa(t + 2), lda, LA + AS(0, 0), tid);
    rdB(b, LB, AS(0, 1), offB);
    rdA<0>(a, LA, AS(0, 1), offA);  mma16<0>(acc, a, b);
    if(more) issue_unit(fb(t + 2), ldb, LB + AS(0, 0), tid);    // ph4
    rdA<1>(a, LA, AS(0, 1), offA);  mma16<1>(acc, a, b);
    if(more){ VMW(8); } else { VMW(4); }                        // ph5
    __builtin_amdgcn_s_barrier();
    if(more) issue_unit(fa(t + 2) + 32, lda, LA + AS(0, 1), tid);
    rdB(b, LB, AS(1, 0), offB);
    rdA<0>(a, LA, AS(1, 0), offA);  mma16<0>(acc, a, b);
    if(more) issue_unit(fb(t + 2) + 32, ldb, LB + AS(0, 1), tid); // ph6
    rdA<1>(a, LA, AS(1, 0), offA);  mma16<1>(acc, a, b);
    if(more){ VMW(8); } else { VMW(0); }                        // ph7
    __builtin_amdgcn_s_barrier();
    if(more) issue_unit(fa(t + 3), lda, LA + AS(1, 0), tid);
    rdB(b, LB, AS(1, 1), offB);
    rdA<0>(a, LA, AS(1, 1), offA);  mma16<0>(acc, a, b);
    if(more) issue_unit(fb(t + 3), ldb, LB + AS(1, 0), tid);    // ph8
    rdA<1>(a, LA, AS(1, 1), offA);  mma16<1>(acc, a, b);
  }
}

// bijective XCD swizzle (grid n divisible by 8)
DI int xcd_swz(int bid, int n){ const int c = n >> 3; return (bid & 7) * c + (bid >> 3); }

// ---------------- fused Q/K/V^T projections: 256^2 8-phase, all-bf16 ------------
__global__ __launch_bounds__(512, 2)
void proj_qkv(const __bf16* __restrict__ xq, const __bf16* __restrict__ xk,
              const __bf16* __restrict__ xv, const __bf16* __restrict__ Wqb,
              const __bf16* __restrict__ Wkb, const __bf16* __restrict__ Wvb,
              const float* __restrict__ bq, const float* __restrict__ bk,
              const float* __restrict__ bv, __bf16* __restrict__ qb,
              __bf16* __restrict__ kb, __bf16* __restrict__ vbT){
  __shared__ __attribute__((aligned(128))) char L[131072];
  const int z = blockIdx.y, tid = threadIdx.x;
  const int bid = xcd_swz(blockIdx.x, 192);
  const __bf16 *A, *B; const float* bias; __bf16* C;
  long m0, n0, ldc; bool biasm;
  if(z == 0){ A = xq;  B = Wqb; bias = bq; C = qb;
              m0 = (long)(bid / 3) * 256; n0 = (bid % 3) * 256; ldc = DIM; biasm = false; }
  else if(z == 1){ A = xk;  B = Wkb; bias = bk; C = kb;
              m0 = (long)(bid / 3) * 256; n0 = (bid % 3) * 256; ldc = DIM; biasm = false; }
  else {      A = Wvb; B = xv;  bias = bv; C = vbT;
              m0 = (long)(bid / 64) * 256; n0 = (bid % 64) * 256; ldc = TOK; biasm = true; }
  const __bf16* Ar = A + m0 * DIM;
  const __bf16* Br = B + n0 * DIM;
  f32x4 acc[8][4] = {};
  auto fa = [&](int t){ return Ar + t * 64; };
  auto fb = [&](int t){ return Br + t * 64; };
  kloop8(fa, DIM, fb, DIM, DIM / 64, tid, L, acc);

  const int lane = tid & 63, w = tid >> 6;
  const int cl = lane & 15, rq = (lane >> 4) * 4;
  #pragma unroll
  for(int i = 0; i < 8; ++i)
    #pragma unroll
    for(int j = 0; j < 4; ++j){
      const long gc = n0 + (w & 3) * 64 + j * 16 + cl;
      #pragma unroll
      for(int e = 0; e < 4; ++e){
        const long gr = m0 + (w >> 2) * 128 + i * 16 + rq + e;
        C[gr * ldc + gc] = (__bf16)(acc[i][j][e] + bias[biasm ? gr : gc]);
      }
    }
}

// ---------------- QK^T: 2-phase 256q x 128k, fused exp + atomic row-sums --------
__global__ __launch_bounds__(512)
void qk_kernel(const __bf16* __restrict__ qb, const __bf16* __restrict__ kb,
               __bf16* __restrict__ Pc, float* __restrict__ rlsum){
  const int sid = xcd_swz(blockIdx.x, 1088);
  const int b = sid / 272, t2 = sid % 272, tid = threadIdx.x;
  int Qi = (int)((sqrtf(4.0f * t2 + 1.0f) - 1.0f) * 0.5f);
  while((Qi + 1) * (Qi + 2) <= t2) Qi++;
  while(Qi * (Qi + 1) > t2) Qi--;
  const int ki = t2 - Qi * (Qi + 1);
  const __bf16* Aq = qb + ((long)b * SEQ + Qi * 256) * DIM;
  const __bf16* Bk = kb + ((long)b * SEQ + ki * 128) * DIM;
  __shared__ __attribute__((aligned(128))) char As[32768];
  __shared__ __attribute__((aligned(128))) char Bs[16384];
  const int lane = tid & 63, w = tid >> 6;
  const int wr = (w >> 1) * 64, wc = (w & 1) * 64;   // 4M x 2N waves
  f32x4 acc[4][4] = {};
  for(int t = 0; t < DIM / 64; ++t){
    stage<512, 256>(Aq + t * 64, DIM, As, tid);
    stage<512, 128>(Bk + t * 64, DIM, Bs, tid);
    __syncthreads();
    mma_tile(As, Bs, lane, wr, wc, acc);
    __syncthreads();
  }
  const int cl = lane & 15, rq = (lane >> 4) * 4;
  #pragma unroll
  for(int i = 0; i < 4; ++i){
    const int rbase = wr + i * 16;                    // 0..255
    const int qi = 2 * Qi + (rbase >> 7);
    if(ki > qi) continue;                             // fully-masked half-tile
    const bool diag = (ki == qi);
    __bf16* tile = Pc + ((long)b * NTRI + (long)qi * (qi + 1) / 2 + ki) * 16384;
    float rsum[4] = {0.f, 0.f, 0.f, 0.f};
    #pragma unroll
    for(int j = 0; j < 4; ++j){
      const int c = wc + j * 16 + cl;
      #pragma unroll
      for(int e = 0; e < 4; ++e){
        const int rloc = (rbase + rq + e) & 127;
        float p = (diag && c > rloc) ? 0.0f
                  : __expf(fminf(acc[i][j][e] * SCALE, 30.0f));
        tile[rloc * 128 + c] = (__bf16)p;
        rsum[e] += p;
      }
    }
    #pragma unroll
    for(int e = 0; e < 4; ++e){                       // reduce across 16 col-lanes
      float s = rsum[e];
      s += __shfl_xor(s, 1); s += __shfl_xor(s, 2);
      s += __shfl_xor(s, 4); s += __shfl_xor(s, 8);
      if(cl == 0){
        const long gr = (long)b * SEQ + Qi * 256 + rbase + rq + e;
        atomicAdd(&rlsum[gr], s);
      }
    }
  }
}

// ---------------- P.V: balanced 3-way K-split, partials to att0/att1/att2 --------
// y-map (long chunks first): y<30: qi=31-y/3 (3 chunks); y<52: qi=21-(y-30)/2
// (2 chunks); else qi=10-(y-52) (1 chunk). Max chunk = 11 P-tiles = 22 BK-steps.
__global__ __launch_bounds__(512)
void pv_kernel(const __bf16* __restrict__ Pc, const float* __restrict__ rlsum,
               const __bf16* __restrict__ vbT, __bf16* __restrict__ att0,
               __bf16* __restrict__ att1, __bf16* __restrict__ att2){
  __shared__ __attribute__((aligned(128))) char As[16384];
  __shared__ __attribute__((aligned(128))) char Bs[32768];
  __shared__ float sRl[128];
  const int x = blockIdx.x, y = blockIdx.y, tid = threadIdx.x;
  const long n0 = (long)(x >> 2) * 256;
  const int b = x & 3;
  int qi, ch, nch;
  if(y < 30){ qi = 31 - y / 3; ch = y % 3; nch = 3; }
  else if(y < 52){ qi = 21 - (y - 30) / 2; ch = (y - 30) & 1; nch = 2; }
  else { qi = 10 - (y - 52); ch = 0; nch = 1; }
  const int ntile = qi + 1, base = ntile / nch, rem = ntile % nch;
  const int k0 = ch * base + (ch < rem ? ch : rem);
  const int sz = base + (ch < rem ? 1 : 0);
  if(tid < 128) sRl[tid] = 1.0f / rlsum[b * SEQ + qi * 128 + tid];
  const __bf16* Pq = Pc + ((long)b * NTRI + (long)qi * (qi + 1) / 2) * 16384;
  const __bf16* Bv = vbT + n0 * TOK + (long)b * SEQ;
  f32x4 acc[4][4] = {};
  auto fa = [&](int t){ return Pq + (long)(k0 + (t >> 1)) * 16384 + (t & 1) * 64; };
  auto fb = [&](int t){ return Bv + (long)k0 * 128 + t * 64; };
  kloop2(fa, 128, fb, TOK, 2 * sz, tid, As, Bs, acc);   // barriers cover sRl

  __bf16* dst = ch == 0 ? att0 : (ch == 1 ? att1 : att2);
  const int lane = tid & 63, w = tid >> 6;
  const int wr = (w >> 2) * 64, wc = (w & 3) * 64;
  const int cl = lane & 15, rq = (lane >> 4) * 4;
  #pragma unroll
  for(int i = 0; i < 4; ++i)
    #pragma unroll
    for(int j = 0; j < 4; ++j){
      const long gc = n0 + wc + j * 16 + cl;
      #pragma unroll
      for(int e = 0; e < 4; ++e){
        const int rloc = wr + i * 16 + rq + e;
        float v = acc[i][j][e] * sRl[rloc];
        dst[((long)b * SEQ + qi * 128 + rloc) * DIM + gc] = (__bf16)v;
      }
    }
  // chunk-0 blocks of qi with <3 chunks zero the unwritten partial rows
  if(ch == 0 && nch < 3){
    const int r = tid >> 2;
    const int c0 = (tid & 3) * 64;
    const long rowoff = ((long)b * SEQ + qi * 128 + r) * DIM + n0 + c0;
    bf16x8 zz = {};
    #pragma unroll
    for(int i = 0; i < 8; ++i) *(bf16x8*)(att2 + rowoff + i * 8) = zz;
    if(nch < 2){
      #pragma unroll
      for(int i = 0; i < 8; ++i) *(bf16x8*)(att1 + rowoff + i * 8) = zz;
    }
  }
}

// ---------------- output projection: A = att0+att1+att2 (fused add) -> fp32 -----
__global__ __launch_bounds__(512)
void oproj(const __bf16* __restrict__ att0, const __bf16* __restrict__ att1,
           const __bf16* __restrict__ att2, const __bf16* __restrict__ Wob,
           const float* __restrict__ bo, float* __restrict__ out){
  __shared__ __attribute__((aligned(128))) char As[16384];
  __shared__ __attribute__((aligned(128))) char Bs[32768];
  const int bid = blockIdx.x, tid = threadIdx.x;
  const long n0 = (bid % 3) * 256, m0 = (long)(bid / 3) * 128;
  const __bf16* Br = Wob + n0 * DIM;
  f32x4 acc[4][4] = {};
  const int lane = tid & 63, w = tid >> 6;
  const int wr = (w >> 2) * 64, wc = (w & 3) * 64;
  for(int t = 0; t < DIM / 64; ++t){
    stage_add3<512, 128>(att0 + m0 * DIM + t * 64, att1 + m0 * DIM + t * 64,
                         att2 + m0 * DIM + t * 64, DIM, As, tid);
    stage<512, 256>(Br + t * 64, DIM, Bs, tid);
    __syncthreads();
    mma_tile(As, Bs, lane, wr, wc, acc);
    __syncthreads();
  }
  const int cl = lane & 15, rq = (lane >> 4) * 4;
  #pragma unroll
  for(int i = 0; i < 4; ++i)
    #pragma unroll
    for(int j = 0; j < 4; ++j){
      const long gc = n0 + wc + j * 16 + cl;
      #pragma unroll
      for(int e = 0; e < 4; ++e){
        const long gr = m0 + wr + i * 16 + rq + e;
        out[gr * DIM + gc] = acc[i][j][e] + bo[gc];
      }
    }
}

// ---------------- launch ----------------
extern "C" void kernel_launch(void* const* d_in, const int* in_sizes, int n_in,
                              void* d_out, int out_size, void* d_ws, size_t ws_size,
                              hipStream_t stream){
  const float* query = (const float*)d_in[0];
  const float* key_  = (const float*)d_in[1];
  const float* value = (const float*)d_in[2];
  const float* Wq = (const float*)d_in[3];
  const float* bq = (const float*)d_in[4];
  const float* Wk = (const float*)d_in[5];
  const float* bk = (const float*)d_in[6];
  const float* Wv = (const float*)d_in[7];
  const float* bv = (const float*)d_in[8];
  const float* Wo = (const float*)d_in[9];
  const float* bo = (const float*)d_in[10];
  // d_in[11]: causal tril mask — implemented structurally (block-triangular P).

  char* p = (char*)d_ws;
  auto carve = [&](size_t bytes)->char*{
    char* r = p; p += (bytes + 255) & ~(size_t)255; return r;
  };
  const size_t tb = (size_t)TOK * DIM * 2;   // 25.2 MB
  __bf16* xq  = (__bf16*)carve(tb);
  __bf16* xk  = (__bf16*)carve(tb);
  __bf16* xv  = (__bf16*)carve(tb);
  __bf16* qb  = (__bf16*)carve(tb);
  __bf16* kb  = (__bf16*)carve(tb);
  __bf16* vbT = (__bf16*)carve(tb);
  __bf16* Wqb = (__bf16*)carve((size_t)DIM * DIM * 2);
  __bf16* Wkb = (__bf16*)carve((size_t)DIM * DIM * 2);
  __bf16* Wvb = (__bf16*)carve((size_t)DIM * DIM * 2);
  __bf16* Wob = (__bf16*)carve((size_t)DIM * DIM * 2);
  __bf16* Pc  = (__bf16*)carve((size_t)BATCH * NTRI * 16384 * 2);  // 69.2 MB
  float*  rlr = (float*)carve((size_t)TOK * 4);
  __bf16* att0 = xq;                          // xq/xk/xv dead after proj
  __bf16* att1 = xk;
  __bf16* att2 = xv;
  if((size_t)(p - (char*)d_ws) > ws_size) return;

  const long nIn4 = TOK * DIM / 4, nW4 = (long)DIM * DIM / 4;
  hipMemsetAsync(rlr, 0, (size_t)TOK * 4, stream);     // row-sum accumulators
  cvt_all<<<dim3(2048, 7), 256, 0, stream>>>(query, key_, value, Wq, Wk, Wv, Wo,
                                             xq, xk, xv, Wqb, Wkb, Wvb, Wob,
                                             nIn4, nW4);

  // Q, K, V^T projections: 256^2 8-phase all-bf16
  proj_qkv<<<dim3(192, 3), 512, 0, stream>>>(xq, xk, xv, Wqb, Wkb, Wvb,
                                             bq, bk, bv, qb, kb, vbT);

  // QK^T with fused exp + row-sum atomics; XCD-swizzled 1D grid (1088 = 8*136)
  qk_kernel<<<1088, 512, 0, stream>>>(qb, kb, Pc, rlr);

  // P.V with balanced 3-way K-split (756 blocks, max 22 BK-steps per block)
  pv_kernel<<<dim3(12, 63), 512, 0, stream>>>(Pc, rlr, vbT, att0, att1, att2);

  // output projection, att0+att1+att2 fused into A-staging -> fp32 d_out
  oproj<<<384, 512, 0, stream>>>(att0, att1, att2, Wob, bo, (float*)d_out);
}

// Round 14
// 292.071 us; speedup vs baseline: 1.0717x; 1.0717x over previous
//
#include <hip/hip_runtime.h>
#include <hip/hip_bf16.h>
#include <stdint.h>

#define DI __device__ __forceinline__

typedef __bf16 bf16x4 __attribute__((ext_vector_type(4)));
typedef __bf16 bf16x8 __attribute__((ext_vector_type(8)));
typedef float  f32x4  __attribute__((ext_vector_type(4)));

static constexpr int  BATCH = 4;
static constexpr int  SEQ   = 4096;
static constexpr int  DIM   = 768;
static constexpr long TOK   = (long)BATCH * SEQ;        // 16384
static constexpr int  QT    = SEQ / 128;                // 32 q-tiles per batch
static constexpr int  NTRI  = QT * (QT + 1) / 2;        // 528 causal 128x128 tiles
static constexpr float SCALE = 0.0360843918243516150f;  // 1/sqrt(768)

// ---------------- fp32 -> bf16 converts ----------------
__global__ void cvt3_kernel(const float* __restrict__ a, const float* __restrict__ b,
                            const float* __restrict__ c, __bf16* __restrict__ oa,
                            __bf16* __restrict__ ob, __bf16* __restrict__ oc, long n4){
  const float* in  = blockIdx.y == 0 ? a : blockIdx.y == 1 ? b : c;
  __bf16*      out = blockIdx.y == 0 ? oa : blockIdx.y == 1 ? ob : oc;
  long i = (long)blockIdx.x * blockDim.x + threadIdx.x;
  const long stride = (long)gridDim.x * blockDim.x;
  for(; i < n4; i += stride){
    float4 v = ((const float4*)in)[i];
    bf16x4 o = { (__bf16)v.x, (__bf16)v.y, (__bf16)v.z, (__bf16)v.w };
    ((bf16x4*)out)[i] = o;
  }
}
__global__ void cvt4_kernel(const float* __restrict__ a, const float* __restrict__ b,
                            const float* __restrict__ c, const float* __restrict__ d,
                            __bf16* __restrict__ oa, __bf16* __restrict__ ob,
                            __bf16* __restrict__ oc, __bf16* __restrict__ od, long n4){
  const float* in  = blockIdx.y == 0 ? a : blockIdx.y == 1 ? b : blockIdx.y == 2 ? c : d;
  __bf16*      out = blockIdx.y == 0 ? oa : blockIdx.y == 1 ? ob : blockIdx.y == 2 ? oc : od;
  long i = (long)blockIdx.x * blockDim.x + threadIdx.x;
  const long stride = (long)gridDim.x * blockDim.x;
  for(; i < n4; i += stride){
    float4 v = ((const float4*)in)[i];
    bf16x4 o = { (__bf16)v.x, (__bf16)v.y, (__bf16)v.z, (__bf16)v.w };
    ((bf16x4*)out)[i] = o;
  }
}

// ================= proven 2-phase core (qk / pv / oproj) =================
// LDS tile: [R rows][64 bf16 = 8 chunks of 16B], chunk XOR-swizzled by (row&7).
DI int swz_off(int r, int c){ return (r << 7) + ((c ^ (r & 7)) << 4); }

template<int NT, int R>
DI void stage(const __bf16* __restrict__ src, long ld, char* lds, int tid){
  const int w = tid >> 6, l = tid & 63;
  const int rsub = l >> 3;
  const int kc   = (l & 7) ^ rsub;
  const __bf16* g = src + (long)(w * 8 + rsub) * ld + kc * 8;
  char* d = lds + (w << 10);
  constexpr int RPC = NT / 8;
  #pragma unroll
  for(int i = 0; i < R / RPC; ++i){
    __builtin_amdgcn_global_load_lds(
        (const __attribute__((address_space(1))) void*)(g + (long)(i * RPC) * ld),
        (__attribute__((address_space(3))) void*)(d + i * RPC * 128), 16, 0, 0);
  }
}

// dual bf16 source, summed (oproj A = att0 + att1), same layout.
template<int NT, int R>
DI void stage_add(const __bf16* __restrict__ a0, const __bf16* __restrict__ a1,
                  long ld, char* lds, int tid){
  const int w = tid >> 6, l = tid & 63;
  const int rsub = l >> 3;
  const int kc   = (l & 7) ^ rsub;
  const long off = (long)(w * 8 + rsub) * ld + kc * 8;
  char* d = lds + (w << 10) + (l << 4);
  constexpr int RPC = NT / 8;
  #pragma unroll
  for(int i = 0; i < R / RPC; ++i){
    bf16x8 v0 = *(const bf16x8*)(a0 + off + (long)(i * RPC) * ld);
    bf16x8 v1 = *(const bf16x8*)(a1 + off + (long)(i * RPC) * ld);
    bf16x8 o;
    #pragma unroll
    for(int e = 0; e < 8; ++e) o[e] = (__bf16)((float)v0[e] + (float)v1[e]);
    *(bf16x8*)(d + i * RPC * 128) = o;
  }
}

DI bf16x8 frag_ld(const char* lds, int row, int c){
  return *(const bf16x8*)(lds + swz_off(row, c));
}

// One K=64 step: 32 MFMAs per wave (4x4 frags x 2 k-halves).
DI void mma_tile(const char* As, const char* Bs, int lane, int wr, int wc, f32x4 acc[4][4]){
  #pragma unroll
  for(int kk = 0; kk < 2; ++kk){
    const int c = kk * 4 + (lane >> 4);
    bf16x8 a[4], b[4];
    #pragma unroll
    for(int i = 0; i < 4; ++i) a[i] = frag_ld(As, wr + i * 16 + (lane & 15), c);
    #pragma unroll
    for(int j = 0; j < 4; ++j) b[j] = frag_ld(Bs, wc + j * 16 + (lane & 15), c);
    #pragma unroll
    for(int i = 0; i < 4; ++i)
      #pragma unroll
      for(int j = 0; j < 4; ++j)
        acc[i][j] = __builtin_amdgcn_mfma_f32_16x16x32_bf16(a[i], b[j], acc[i][j], 0, 0, 0);
  }
}

// Single-buffered 128x256 K-loop (48KB LDS -> 3 blocks/CU), all-bf16 operands.
template<class FA, class FB>
DI void kloop2(FA fa, long lda, FB fb, long ldb, int nt, int tid,
               char* As, char* Bs, f32x4 acc[4][4]){
  const int lane = tid & 63, w = tid >> 6;
  const int wr = (w >> 2) * 64, wc = (w & 3) * 64;
  for(int t = 0; t < nt; ++t){
    stage<512, 128>(fa(t), lda, As, tid);
    stage<512, 256>(fb(t), ldb, Bs, tid);
    __syncthreads();
    mma_tile(As, Bs, lane, wr, wc, acc);
    __syncthreads();
  }
}

// ================= round-6-verified 256x256 8-phase core (proj) =================
DI void issue_unit(const __bf16* __restrict__ src, long ld, char* slab, int tid){
  const int w = tid >> 6, lane = tid & 63;
  #pragma unroll
  for(int r = 0; r < 2; ++r){
    const int row = w * 16 + (lane >> 2) + r * 128;
    const int c   = (lane & 3) ^ ((row >> 1) & 3);
    const __bf16* g = src + (long)row * ld + c * 8;
    __builtin_amdgcn_global_load_lds(
        (const __attribute__((address_space(1))) void*)g,
        (__attribute__((address_space(3))) void*)(slab + w * 1024 + r * 8192), 16, 0, 0);
  }
}

template<int G>
DI void mma16(f32x4 (&acc)[8][4], const bf16x8 (&a)[4], const bf16x8 (&b)[4]){
  __builtin_amdgcn_s_setprio(1);
  #pragma unroll
  for(int i = 0; i < 4; ++i)
    #pragma unroll
    for(int j = 0; j < 4; ++j)
      acc[G * 4 + i][j] =
          __builtin_amdgcn_mfma_f32_16x16x32_bf16(a[i], b[j], acc[G * 4 + i][j], 0, 0, 0);
  __builtin_amdgcn_s_setprio(0);
}
template<int G>
DI void rdA(bf16x8 (&a)[4], const char* LA, int sbase, const int (&offA)[8]){
  #pragma unroll
  for(int i = 0; i < 4; ++i) a[i] = *(const bf16x8*)(LA + sbase + offA[G * 4 + i]);
}
DI void rdB(bf16x8 (&b)[4], const char* LB, int sbase, const int (&offB)[4]){
  #pragma unroll
  for(int j = 0; j < 4; ++j) b[j] = *(const bf16x8*)(LB + sbase + offB[j]);
}
#define VMW(N) asm volatile("s_waitcnt vmcnt(" #N ")" ::: "memory")

template<class FA, class FB>
DI void kloop8(FA fa, long lda, FB fb, long ldb, int nt, int tid,
               char* L, f32x4 (&acc)[8][4]){
  const int lane = tid & 63, w = tid >> 6;
  int offA[8], offB[4];
  #pragma unroll
  for(int i = 0; i < 8; ++i){
    const int r = (w >> 2) * 128 + i * 16 + (lane & 15);
    offA[i] = r * 64 + ((((lane >> 4)) ^ ((r >> 1) & 3)) << 4);
  }
  #pragma unroll
  for(int j = 0; j < 4; ++j){
    const int r = (w & 3) * 64 + j * 16 + (lane & 15);
    offB[j] = r * 64 + ((((lane >> 4)) ^ ((r >> 1) & 3)) << 4);
  }
  char* LA = L;
  char* LB = L + 65536;
  auto AS = [](int s, int k){ return s * 32768 + k * 16384; };
  issue_unit(fa(0),      lda, LA + AS(0, 0), tid);
  issue_unit(fb(0),      ldb, LB + AS(0, 0), tid);
  issue_unit(fa(0) + 32, lda, LA + AS(0, 1), tid);
  issue_unit(fb(0) + 32, ldb, LB + AS(0, 1), tid);
  issue_unit(fa(1),      lda, LA + AS(1, 0), tid);
  issue_unit(fb(1),      ldb, LB + AS(1, 0), tid);
  bf16x8 a[4], b[4];
  for(int t = 0; t < nt; t += 2){
    const bool more = (t + 2 < nt);
    VMW(8); __builtin_amdgcn_s_barrier();                       // ph1
    issue_unit(fa(t + 1) + 32, lda, LA + AS(1, 1), tid);
    rdB(b, LB, AS(0, 0), offB);
    rdA<0>(a, LA, AS(0, 0), offA);  mma16<0>(acc, a, b);
    issue_unit(fb(t + 1) + 32, ldb, LB + AS(1, 1), tid);        // ph2
    rdA<1>(a, LA, AS(0, 0), offA);  mma16<1>(acc, a, b);
    VMW(8); __builtin_amdgcn_s_barrier();                       // ph3
    if(more) issue_unit(fa(t + 2), lda, LA + AS(0, 0), tid);
    rdB(b, LB, AS(0, 1), offB);
    rdA<0>(a, LA, AS(0, 1), offA);  mma16<0>(acc, a, b);
    if(more) issue_unit(fb(t + 2), ldb, LB + AS(0, 0), tid);    // ph4
    rdA<1>(a, LA, AS(0, 1), offA);  mma16<1>(acc, a, b);
    if(more){ VMW(8); } else { VMW(4); }                        // ph5
    __builtin_amdgcn_s_barrier();
    if(more) issue_unit(fa(t + 2) + 32, lda, LA + AS(0, 1), tid);
    rdB(b, LB, AS(1, 0), offB);
    rdA<0>(a, LA, AS(1, 0), offA);  mma16<0>(acc, a, b);
    if(more) issue_unit(fb(t + 2) + 32, ldb, LB + AS(0, 1), tid); // ph6
    rdA<1>(a, LA, AS(1, 0), offA);  mma16<1>(acc, a, b);
    if(more){ VMW(8); } else { VMW(0); }                        // ph7
    __builtin_amdgcn_s_barrier();
    if(more) issue_unit(fa(t + 3), lda, LA + AS(1, 0), tid);
    rdB(b, LB, AS(1, 1), offB);
    rdA<0>(a, LA, AS(1, 1), offA);  mma16<0>(acc, a, b);
    if(more) issue_unit(fb(t + 3), ldb, LB + AS(1, 0), tid);    // ph8
    rdA<1>(a, LA, AS(1, 1), offA);  mma16<1>(acc, a, b);
  }
}

// bijective XCD swizzle (grid n divisible by 8)
DI int xcd_swz(int bid, int n){ const int c = n >> 3; return (bid & 7) * c + (bid >> 3); }

// ---------------- fused Q/K/V^T projections: 256^2 8-phase, all-bf16 ------------
__global__ __launch_bounds__(512, 2)
void proj_qkv(const __bf16* __restrict__ xq, const __bf16* __restrict__ xk,
              const __bf16* __restrict__ xv, const __bf16* __restrict__ Wqb,
              const __bf16* __restrict__ Wkb, const __bf16* __restrict__ Wvb,
              const float* __restrict__ bq, const float* __restrict__ bk,
              const float* __restrict__ bv, __bf16* __restrict__ qb,
              __bf16* __restrict__ kb, __bf16* __restrict__ vbT){
  __shared__ __attribute__((aligned(128))) char L[131072];
  const int z = blockIdx.y, tid = threadIdx.x;
  const int bid = xcd_swz(blockIdx.x, 192);
  const __bf16 *A, *B; const float* bias; __bf16* C;
  long m0, n0, ldc; bool biasm;
  if(z == 0){ A = xq;  B = Wqb; bias = bq; C = qb;
              m0 = (long)(bid / 3) * 256; n0 = (bid % 3) * 256; ldc = DIM; biasm = false; }
  else if(z == 1){ A = xk;  B = Wkb; bias = bk; C = kb;
              m0 = (long)(bid / 3) * 256; n0 = (bid % 3) * 256; ldc = DIM; biasm = false; }
  else {      A = Wvb; B = xv;  bias = bv; C = vbT;
              m0 = (long)(bid / 64) * 256; n0 = (bid % 64) * 256; ldc = TOK; biasm = true; }
  const __bf16* Ar = A + m0 * DIM;
  const __bf16* Br = B + n0 * DIM;
  f32x4 acc[8][4] = {};
  auto fa = [&](int t){ return Ar + t * 64; };
  auto fb = [&](int t){ return Br + t * 64; };
  kloop8(fa, DIM, fb, DIM, DIM / 64, tid, L, acc);

  const int lane = tid & 63, w = tid >> 6;
  const int cl = lane & 15, rq = (lane >> 4) * 4;
  #pragma unroll
  for(int i = 0; i < 8; ++i)
    #pragma unroll
    for(int j = 0; j < 4; ++j){
      const long gc = n0 + (w & 3) * 64 + j * 16 + cl;
      #pragma unroll
      for(int e = 0; e < 4; ++e){
        const long gr = m0 + (w >> 2) * 128 + i * 16 + rq + e;
        C[gr * ldc + gc] = (__bf16)(acc[i][j][e] + bias[biasm ? gr : gc]);
      }
    }
}

// ---------------- QK^T: 2-phase 128q x 128k, 256 threads, 5 blocks/CU ----------
// 2112 = 8*264 blocks (fill 82.5% vs 71% at 256q tiling); fused exp + row-sums.
__global__ __launch_bounds__(256)
void qk_kernel(const __bf16* __restrict__ qb, const __bf16* __restrict__ kb,
               __bf16* __restrict__ Pc, float* __restrict__ rlsum){
  const int sid = xcd_swz(blockIdx.x, 2112);
  const int b = sid / 528, t = sid % 528, tid = threadIdx.x;
  int qi = (int)((sqrtf(8.0f * t + 1.0f) - 1.0f) * 0.5f);
  while((qi + 1) * (qi + 2) / 2 <= t) qi++;
  while(qi * (qi + 1) / 2 > t) qi--;
  const int ki = t - qi * (qi + 1) / 2;
  const __bf16* Aq = qb + ((long)b * SEQ + qi * 128) * DIM;
  const __bf16* Bk = kb + ((long)b * SEQ + ki * 128) * DIM;
  __shared__ __attribute__((aligned(128))) char As[16384];
  __shared__ __attribute__((aligned(128))) char Bs[16384];
  const int lane = tid & 63, w = tid >> 6;
  const int wr = (w >> 1) * 64, wc = (w & 1) * 64;   // 2M x 2N waves
  f32x4 acc[4][4] = {};
  for(int tt = 0; tt < DIM / 64; ++tt){
    stage<256, 128>(Aq + tt * 64, DIM, As, tid);
    stage<256, 128>(Bk + tt * 64, DIM, Bs, tid);
    __syncthreads();
    mma_tile(As, Bs, lane, wr, wc, acc);
    __syncthreads();
  }
  const bool diag = (qi == ki);
  __bf16* tile = Pc + ((long)b * NTRI + (long)qi * (qi + 1) / 2 + ki) * 16384;
  const int cl = lane & 15, rq = (lane >> 4) * 4;
  #pragma unroll
  for(int i = 0; i < 4; ++i){
    const int rbase = wr + i * 16;
    float rsum[4] = {0.f, 0.f, 0.f, 0.f};
    #pragma unroll
    for(int j = 0; j < 4; ++j){
      const int c = wc + j * 16 + cl;
      #pragma unroll
      for(int e = 0; e < 4; ++e){
        const int rloc = rbase + rq + e;
        float p = (diag && c > rloc) ? 0.0f
                  : __expf(fminf(acc[i][j][e] * SCALE, 30.0f));
        tile[rloc * 128 + c] = (__bf16)p;
        rsum[e] += p;
      }
    }
    #pragma unroll
    for(int e = 0; e < 4; ++e){                       // reduce across 16 col-lanes
      float s = rsum[e];
      s += __shfl_xor(s, 1); s += __shfl_xor(s, 2);
      s += __shfl_xor(s, 4); s += __shfl_xor(s, 8);
      if(cl == 0){
        const long gr = (long)b * SEQ + qi * 128 + rbase + rq + e;
        atomicAdd(&rlsum[gr], s);
      }
    }
  }
}

// ---------------- P.V: K-split 128x256 GEMM, partials to att0/att1 ----------
__global__ __launch_bounds__(512)
void pv_kernel(const __bf16* __restrict__ Pc, const float* __restrict__ rlsum,
               const __bf16* __restrict__ vbT, __bf16* __restrict__ att0,
               __bf16* __restrict__ att1){
  __shared__ __attribute__((aligned(128))) char As[16384];
  __shared__ __attribute__((aligned(128))) char Bs[32768];
  __shared__ float sRl[128];
  const int x = blockIdx.x, y = blockIdx.y, tid = threadIdx.x;
  const long n0 = (long)(x >> 2) * 256;
  const int b = x & 3;
  int qi, k0, k1, half;
  if(y == 62){ qi = 0; k0 = 0; k1 = 1; half = 0; }
  else{
    qi = 31 - (y >> 1); half = y & 1;
    const int c0 = (qi + 2) >> 1;
    if(half == 0){ k0 = 0; k1 = c0; } else { k0 = c0; k1 = qi + 1; }
  }
  if(tid < 128) sRl[tid] = 1.0f / rlsum[b * SEQ + qi * 128 + tid];
  const __bf16* Pq = Pc + ((long)b * NTRI + (long)qi * (qi + 1) / 2) * 16384;
  const __bf16* Bv = vbT + n0 * TOK + (long)b * SEQ;
  f32x4 acc[4][4] = {};
  auto fa = [&](int t){ return Pq + (long)(k0 + (t >> 1)) * 16384 + (t & 1) * 64; };
  auto fb = [&](int t){ return Bv + (long)k0 * 128 + t * 64; };
  kloop2(fa, 128, fb, TOK, 2 * (k1 - k0), tid, As, Bs, acc);  // barriers cover sRl

  __bf16* dst = half ? att1 : att0;
  const int lane = tid & 63, w = tid >> 6;
  const int wr = (w >> 2) * 64, wc = (w & 3) * 64;
  const int cl = lane & 15, rq = (lane >> 4) * 4;
  #pragma unroll
  for(int i = 0; i < 4; ++i)
    #pragma unroll
    for(int j = 0; j < 4; ++j){
      const long gc = n0 + wc + j * 16 + cl;
      #pragma unroll
      for(int e = 0; e < 4; ++e){
        const int rloc = wr + i * 16 + rq + e;
        float v = acc[i][j][e] * sRl[rloc];
        dst[((long)b * SEQ + qi * 128 + rloc) * DIM + gc] = (__bf16)v;
      }
    }
  if(y == 62){
    // qi=0 rows of att1 are never written by half=1 blocks: zero them here.
    const int r = tid >> 2;
    const int c0 = (tid & 3) * 64;
    __bf16* z0 = att1 + ((long)b * SEQ + r) * DIM + n0 + c0;
    bf16x8 zz = {};
    #pragma unroll
    for(int i = 0; i < 8; ++i) *(bf16x8*)(z0 + i * 8) = zz;
  }
}

// ---------------- output projection: A = att0+att1 (fused add) -> fp32 ----------
__global__ __launch_bounds__(512)
void oproj(const __bf16* __restrict__ att0, const __bf16* __restrict__ att1,
           const __bf16* __restrict__ Wob, const float* __restrict__ bo,
           float* __restrict__ out){
  __shared__ __attribute__((aligned(128))) char As[16384];
  __shared__ __attribute__((aligned(128))) char Bs[32768];
  const int bid = blockIdx.x, tid = threadIdx.x;
  const long n0 = (bid % 3) * 256, m0 = (long)(bid / 3) * 128;
  const __bf16* Br = Wob + n0 * DIM;
  f32x4 acc[4][4] = {};
  const int lane = tid & 63, w = tid >> 6;
  const int wr = (w >> 2) * 64, wc = (w & 3) * 64;
  for(int t = 0; t < DIM / 64; ++t){
    stage_add<512, 128>(att0 + m0 * DIM + t * 64, att1 + m0 * DIM + t * 64, DIM, As, tid);
    stage<512, 256>(Br + t * 64, DIM, Bs, tid);
    __syncthreads();
    mma_tile(As, Bs, lane, wr, wc, acc);
    __syncthreads();
  }
  const int cl = lane & 15, rq = (lane >> 4) * 4;
  #pragma unroll
  for(int i = 0; i < 4; ++i)
    #pragma unroll
    for(int j = 0; j < 4; ++j){
      const long gc = n0 + wc + j * 16 + cl;
      #pragma unroll
      for(int e = 0; e < 4; ++e){
        const long gr = m0 + wr + i * 16 + rq + e;
        out[gr * DIM + gc] = acc[i][j][e] + bo[gc];
      }
    }
}

// ---------------- launch ----------------
extern "C" void kernel_launch(void* const* d_in, const int* in_sizes, int n_in,
                              void* d_out, int out_size, void* d_ws, size_t ws_size,
                              hipStream_t stream){
  const float* query = (const float*)d_in[0];
  const float* key_  = (const float*)d_in[1];
  const float* value = (const float*)d_in[2];
  const float* Wq = (const float*)d_in[3];
  const float* bq = (const float*)d_in[4];
  const float* Wk = (const float*)d_in[5];
  const float* bk = (const float*)d_in[6];
  const float* Wv = (const float*)d_in[7];
  const float* bv = (const float*)d_in[8];
  const float* Wo = (const float*)d_in[9];
  const float* bo = (const float*)d_in[10];
  // d_in[11]: causal tril mask — implemented structurally (block-triangular P).

  char* p = (char*)d_ws;
  auto carve = [&](size_t bytes)->char*{
    char* r = p; p += (bytes + 255) & ~(size_t)255; return r;
  };
  const size_t tb = (size_t)TOK * DIM * 2;   // 25.2 MB
  __bf16* xq  = (__bf16*)carve(tb);
  __bf16* xk  = (__bf16*)carve(tb);
  __bf16* xv  = (__bf16*)carve(tb);
  __bf16* qb  = (__bf16*)carve(tb);
  __bf16* kb  = (__bf16*)carve(tb);
  __bf16* vbT = (__bf16*)carve(tb);
  __bf16* Wqb = (__bf16*)carve((size_t)DIM * DIM * 2);
  __bf16* Wkb = (__bf16*)carve((size_t)DIM * DIM * 2);
  __bf16* Wvb = (__bf16*)carve((size_t)DIM * DIM * 2);
  __bf16* Wob = (__bf16*)carve((size_t)DIM * DIM * 2);
  __bf16* Pc  = (__bf16*)carve((size_t)BATCH * NTRI * 16384 * 2);  // 69.2 MB
  float*  rlr = (float*)carve((size_t)TOK * 4);
  __bf16* att0 = xq;                          // xq, xk dead after proj
  __bf16* att1 = xk;
  if((size_t)(p - (char*)d_ws) > ws_size) return;

  const long nIn4 = TOK * DIM / 4, nW4 = (long)DIM * DIM / 4;
  dim3 g3(2048, 3), g4((unsigned)((nW4 + 255) / 256), 4);
  hipMemsetAsync(rlr, 0, (size_t)TOK * 4, stream);     // row-sum accumulators
  cvt3_kernel<<<g3, 256, 0, stream>>>(query, key_, value, xq, xk, xv, nIn4);
  cvt4_kernel<<<g4, 256, 0, stream>>>(Wq, Wk, Wv, Wo, Wqb, Wkb, Wvb, Wob, nW4);

  // Q, K, V^T projections: 256^2 8-phase all-bf16
  proj_qkv<<<dim3(192, 3), 512, 0, stream>>>(xq, xk, xv, Wqb, Wkb, Wvb,
                                             bq, bk, bv, qb, kb, vbT);

  // QK^T: 128x128 tiles, 5 blocks/CU, XCD-swizzled (2112 = 8*264)
  qk_kernel<<<2112, 256, 0, stream>>>(qb, kb, Pc, rlr);

  // P.V with balanced 2-way K-split (756 blocks, longest chunks first)
  pv_kernel<<<dim3(12, 63), 512, 0, stream>>>(Pc, rlr, vbT, att0, att1);

  // output projection, att0+att1 fused into A-staging -> fp32 d_out
  oproj<<<384, 512, 0, stream>>>(att0, att1, Wob, bo, (float*)d_out);
}

// Round 15
// 285.923 us; speedup vs baseline: 1.0948x; 1.0215x over previous
//
#include <hip/hip_runtime.h>
#include <hip/hip_bf16.h>
#include <stdint.h>

#define DI __device__ __forceinline__

typedef __bf16 bf16x4 __attribute__((ext_vector_type(4)));
typedef __bf16 bf16x8 __attribute__((ext_vector_type(8)));
typedef float  f32x4  __attribute__((ext_vector_type(4)));

static constexpr int  BATCH = 4;
static constexpr int  SEQ   = 4096;
static constexpr int  DIM   = 768;
static constexpr long TOK   = (long)BATCH * SEQ;        // 16384
static constexpr int  QT    = SEQ / 128;                // 32 q-tiles per batch
static constexpr int  NTRI  = QT * (QT + 1) / 2;        // 528 causal 128x128 tiles
static constexpr float SCALE = 0.0360843918243516150f;  // 1/sqrt(768)

// ---------------- fp32 -> bf16 converts ----------------
__global__ void cvt3_kernel(const float* __restrict__ a, const float* __restrict__ b,
                            const float* __restrict__ c, __bf16* __restrict__ oa,
                            __bf16* __restrict__ ob, __bf16* __restrict__ oc, long n4){
  const float* in  = blockIdx.y == 0 ? a : blockIdx.y == 1 ? b : c;
  __bf16*      out = blockIdx.y == 0 ? oa : blockIdx.y == 1 ? ob : oc;
  long i = (long)blockIdx.x * blockDim.x + threadIdx.x;
  const long stride = (long)gridDim.x * blockDim.x;
  for(; i < n4; i += stride){
    float4 v = ((const float4*)in)[i];
    bf16x4 o = { (__bf16)v.x, (__bf16)v.y, (__bf16)v.z, (__bf16)v.w };
    ((bf16x4*)out)[i] = o;
  }
}
__global__ void cvt4_kernel(const float* __restrict__ a, const float* __restrict__ b,
                            const float* __restrict__ c, const float* __restrict__ d,
                            __bf16* __restrict__ oa, __bf16* __restrict__ ob,
                            __bf16* __restrict__ oc, __bf16* __restrict__ od, long n4){
  const float* in  = blockIdx.y == 0 ? a : blockIdx.y == 1 ? b : blockIdx.y == 2 ? c : d;
  __bf16*      out = blockIdx.y == 0 ? oa : blockIdx.y == 1 ? ob : blockIdx.y == 2 ? oc : od;
  long i = (long)blockIdx.x * blockDim.x + threadIdx.x;
  const long stride = (long)gridDim.x * blockDim.x;
  for(; i < n4; i += stride){
    float4 v = ((const float4*)in)[i];
    bf16x4 o = { (__bf16)v.x, (__bf16)v.y, (__bf16)v.z, (__bf16)v.w };
    ((bf16x4*)out)[i] = o;
  }
}

// ================= proven 2-phase core (qk / pv / oproj) =================
// LDS tile: [R rows][64 bf16 = 8 chunks of 16B], chunk XOR-swizzled by (row&7).
DI int swz_off(int r, int c){ return (r << 7) + ((c ^ (r & 7)) << 4); }

template<int NT, int R>
DI void stage(const __bf16* __restrict__ src, long ld, char* lds, int tid){
  const int w = tid >> 6, l = tid & 63;
  const int rsub = l >> 3;
  const int kc   = (l & 7) ^ rsub;
  const __bf16* g = src + (long)(w * 8 + rsub) * ld + kc * 8;
  char* d = lds + (w << 10);
  constexpr int RPC = NT / 8;
  #pragma unroll
  for(int i = 0; i < R / RPC; ++i){
    __builtin_amdgcn_global_load_lds(
        (const __attribute__((address_space(1))) void*)(g + (long)(i * RPC) * ld),
        (__attribute__((address_space(3))) void*)(d + i * RPC * 128), 16, 0, 0);
  }
}

// dual bf16 source, summed (oproj A = att0 + att1), same layout.
template<int NT, int R>
DI void stage_add(const __bf16* __restrict__ a0, const __bf16* __restrict__ a1,
                  long ld, char* lds, int tid){
  const int w = tid >> 6, l = tid & 63;
  const int rsub = l >> 3;
  const int kc   = (l & 7) ^ rsub;
  const long off = (long)(w * 8 + rsub) * ld + kc * 8;
  char* d = lds + (w << 10) + (l << 4);
  constexpr int RPC = NT / 8;
  #pragma unroll
  for(int i = 0; i < R / RPC; ++i){
    bf16x8 v0 = *(const bf16x8*)(a0 + off + (long)(i * RPC) * ld);
    bf16x8 v1 = *(const bf16x8*)(a1 + off + (long)(i * RPC) * ld);
    bf16x8 o;
    #pragma unroll
    for(int e = 0; e < 8; ++e) o[e] = (__bf16)((float)v0[e] + (float)v1[e]);
    *(bf16x8*)(d + i * RPC * 128) = o;
  }
}

DI bf16x8 frag_ld(const char* lds, int row, int c){
  return *(const bf16x8*)(lds + swz_off(row, c));
}

// One K=64 step: 32 MFMAs per wave (4x4 frags x 2 k-halves).
DI void mma_tile(const char* As, const char* Bs, int lane, int wr, int wc, f32x4 acc[4][4]){
  #pragma unroll
  for(int kk = 0; kk < 2; ++kk){
    const int c = kk * 4 + (lane >> 4);
    bf16x8 a[4], b[4];
    #pragma unroll
    for(int i = 0; i < 4; ++i) a[i] = frag_ld(As, wr + i * 16 + (lane & 15), c);
    #pragma unroll
    for(int j = 0; j < 4; ++j) b[j] = frag_ld(Bs, wc + j * 16 + (lane & 15), c);
    #pragma unroll
    for(int i = 0; i < 4; ++i)
      #pragma unroll
      for(int j = 0; j < 4; ++j)
        acc[i][j] = __builtin_amdgcn_mfma_f32_16x16x32_bf16(a[i], b[j], acc[i][j], 0, 0, 0);
  }
}

// Single-buffered 128x256 K-loop (48KB LDS -> 3 blocks/CU), all-bf16 operands.
template<class FA, class FB>
DI void kloop2(FA fa, long lda, FB fb, long ldb, int nt, int tid,
               char* As, char* Bs, f32x4 acc[4][4]){
  const int lane = tid & 63, w = tid >> 6;
  const int wr = (w >> 2) * 64, wc = (w & 3) * 64;
  for(int t = 0; t < nt; ++t){
    stage<512, 128>(fa(t), lda, As, tid);
    stage<512, 256>(fb(t), ldb, Bs, tid);
    __syncthreads();
    mma_tile(As, Bs, lane, wr, wc, acc);
    __syncthreads();
  }
}

// ================= round-6-verified 256x256 8-phase core (proj) =================
DI void issue_unit(const __bf16* __restrict__ src, long ld, char* slab, int tid){
  const int w = tid >> 6, lane = tid & 63;
  #pragma unroll
  for(int r = 0; r < 2; ++r){
    const int row = w * 16 + (lane >> 2) + r * 128;
    const int c   = (lane & 3) ^ ((row >> 1) & 3);
    const __bf16* g = src + (long)row * ld + c * 8;
    __builtin_amdgcn_global_load_lds(
        (const __attribute__((address_space(1))) void*)g,
        (__attribute__((address_space(3))) void*)(slab + w * 1024 + r * 8192), 16, 0, 0);
  }
}

template<int G>
DI void mma16(f32x4 (&acc)[8][4], const bf16x8 (&a)[4], const bf16x8 (&b)[4]){
  __builtin_amdgcn_s_setprio(1);
  #pragma unroll
  for(int i = 0; i < 4; ++i)
    #pragma unroll
    for(int j = 0; j < 4; ++j)
      acc[G * 4 + i][j] =
          __builtin_amdgcn_mfma_f32_16x16x32_bf16(a[i], b[j], acc[G * 4 + i][j], 0, 0, 0);
  __builtin_amdgcn_s_setprio(0);
}
template<int G>
DI void rdA(bf16x8 (&a)[4], const char* LA, int sbase, const int (&offA)[8]){
  #pragma unroll
  for(int i = 0; i < 4; ++i) a[i] = *(const bf16x8*)(LA + sbase + offA[G * 4 + i]);
}
DI void rdB(bf16x8 (&b)[4], const char* LB, int sbase, const int (&offB)[4]){
  #pragma unroll
  for(int j = 0; j < 4; ++j) b[j] = *(const bf16x8*)(LB + sbase + offB[j]);
}
#define VMW(N) asm volatile("s_waitcnt vmcnt(" #N ")" ::: "memory")

template<class FA, class FB>
DI void kloop8(FA fa, long lda, FB fb, long ldb, int nt, int tid,
               char* L, f32x4 (&acc)[8][4]){
  const int lane = tid & 63, w = tid >> 6;
  int offA[8], offB[4];
  #pragma unroll
  for(int i = 0; i < 8; ++i){
    const int r = (w >> 2) * 128 + i * 16 + (lane & 15);
    offA[i] = r * 64 + ((((lane >> 4)) ^ ((r >> 1) & 3)) << 4);
  }
  #pragma unroll
  for(int j = 0; j < 4; ++j){
    const int r = (w & 3) * 64 + j * 16 + (lane & 15);
    offB[j] = r * 64 + ((((lane >> 4)) ^ ((r >> 1) & 3)) << 4);
  }
  char* LA = L;
  char* LB = L + 65536;
  auto AS = [](int s, int k){ return s * 32768 + k * 16384; };
  issue_unit(fa(0),      lda, LA + AS(0, 0), tid);
  issue_unit(fb(0),      ldb, LB + AS(0, 0), tid);
  issue_unit(fa(0) + 32, lda, LA + AS(0, 1), tid);
  issue_unit(fb(0) + 32, ldb, LB + AS(0, 1), tid);
  issue_unit(fa(1),      lda, LA + AS(1, 0), tid);
  issue_unit(fb(1),      ldb, LB + AS(1, 0), tid);
  bf16x8 a[4], b[4];
  for(int t = 0; t < nt; t += 2){
    const bool more = (t + 2 < nt);
    VMW(8); __builtin_amdgcn_s_barrier();                       // ph1
    issue_unit(fa(t + 1) + 32, lda, LA + AS(1, 1), tid);
    rdB(b, LB, AS(0, 0), offB);
    rdA<0>(a, LA, AS(0, 0), offA);  mma16<0>(acc, a, b);
    issue_unit(fb(t + 1) + 32, ldb, LB + AS(1, 1), tid);        // ph2
    rdA<1>(a, LA, AS(0, 0), offA);  mma16<1>(acc, a, b);
    VMW(8); __builtin_amdgcn_s_barrier();                       // ph3
    if(more) issue_unit(fa(t + 2), lda, LA + AS(0, 0), tid);
    rdB(b, LB, AS(0, 1), offB);
    rdA<0>(a, LA, AS(0, 1), offA);  mma16<0>(acc, a, b);
    if(more) issue_unit(fb(t + 2), ldb, LB + AS(0, 0), tid);    // ph4
    rdA<1>(a, LA, AS(0, 1), offA);  mma16<1>(acc, a, b);
    if(more){ VMW(8); } else { VMW(4); }                        // ph5
    __builtin_amdgcn_s_barrier();
    if(more) issue_unit(fa(t + 2) + 32, lda, LA + AS(0, 1), tid);
    rdB(b, LB, AS(1, 0), offB);
    rdA<0>(a, LA, AS(1, 0), offA);  mma16<0>(acc, a, b);
    if(more) issue_unit(fb(t + 2) + 32, ldb, LB + AS(0, 1), tid); // ph6
    rdA<1>(a, LA, AS(1, 0), offA);  mma16<1>(acc, a, b);
    if(more){ VMW(8); } else { VMW(0); }                        // ph7
    __builtin_amdgcn_s_barrier();
    if(more) issue_unit(fa(t + 3), lda, LA + AS(1, 0), tid);
    rdB(b, LB, AS(1, 1), offB);
    rdA<0>(a, LA, AS(1, 1), offA);  mma16<0>(acc, a, b);
    if(more) issue_unit(fb(t + 3), ldb, LB + AS(1, 0), tid);    // ph8
    rdA<1>(a, LA, AS(1, 1), offA);  mma16<1>(acc, a, b);
  }
}

// bijective XCD swizzle (grid n divisible by 8)
DI int xcd_swz(int bid, int n){ const int c = n >> 3; return (bid & 7) * c + (bid >> 3); }

// ---------------- fused Q/K/V^T projections: 256^2 8-phase, all-bf16 ------------
__global__ __launch_bounds__(512, 2)
void proj_qkv(const __bf16* __restrict__ xq, const __bf16* __restrict__ xk,
              const __bf16* __restrict__ xv, const __bf16* __restrict__ Wqb,
              const __bf16* __restrict__ Wkb, const __bf16* __restrict__ Wvb,
              const float* __restrict__ bq, const float* __restrict__ bk,
              const float* __restrict__ bv, __bf16* __restrict__ qb,
              __bf16* __restrict__ kb, __bf16* __restrict__ vbT){
  __shared__ __attribute__((aligned(128))) char L[131072];
  const int z = blockIdx.y, tid = threadIdx.x;
  const int bid = xcd_swz(blockIdx.x, 192);
  const __bf16 *A, *B; const float* bias; __bf16* C;
  long m0, n0, ldc; bool biasm;
  if(z == 0){ A = xq;  B = Wqb; bias = bq; C = qb;
              m0 = (long)(bid / 3) * 256; n0 = (bid % 3) * 256; ldc = DIM; biasm = false; }
  else if(z == 1){ A = xk;  B = Wkb; bias = bk; C = kb;
              m0 = (long)(bid / 3) * 256; n0 = (bid % 3) * 256; ldc = DIM; biasm = false; }
  else {      A = Wvb; B = xv;  bias = bv; C = vbT;
              m0 = (long)(bid / 64) * 256; n0 = (bid % 64) * 256; ldc = TOK; biasm = true; }
  const __bf16* Ar = A + m0 * DIM;
  const __bf16* Br = B + n0 * DIM;
  f32x4 acc[8][4] = {};
  auto fa = [&](int t){ return Ar + t * 64; };
  auto fb = [&](int t){ return Br + t * 64; };
  kloop8(fa, DIM, fb, DIM, DIM / 64, tid, L, acc);

  const int lane = tid & 63, w = tid >> 6;
  const int cl = lane & 15, rq = (lane >> 4) * 4;
  #pragma unroll
  for(int i = 0; i < 8; ++i)
    #pragma unroll
    for(int j = 0; j < 4; ++j){
      const long gc = n0 + (w & 3) * 64 + j * 16 + cl;
      #pragma unroll
      for(int e = 0; e < 4; ++e){
        const long gr = m0 + (w >> 2) * 128 + i * 16 + rq + e;
        C[gr * ldc + gc] = (__bf16)(acc[i][j][e] + bias[biasm ? gr : gc]);
      }
    }
}

// ---------------- QK^T: 2-phase 256q x 128k, fused exp + atomic row-sums --------
__global__ __launch_bounds__(512)
void qk_kernel(const __bf16* __restrict__ qb, const __bf16* __restrict__ kb,
               __bf16* __restrict__ Pc, float* __restrict__ rlsum){
  const int sid = xcd_swz(blockIdx.x, 1088);
  const int b = sid / 272, t2 = sid % 272, tid = threadIdx.x;
  int Qi = (int)((sqrtf(4.0f * t2 + 1.0f) - 1.0f) * 0.5f);
  while((Qi + 1) * (Qi + 2) <= t2) Qi++;
  while(Qi * (Qi + 1) > t2) Qi--;
  const int ki = t2 - Qi * (Qi + 1);
  const __bf16* Aq = qb + ((long)b * SEQ + Qi * 256) * DIM;
  const __bf16* Bk = kb + ((long)b * SEQ + ki * 128) * DIM;
  __shared__ __attribute__((aligned(128))) char As[32768];
  __shared__ __attribute__((aligned(128))) char Bs[16384];
  const int lane = tid & 63, w = tid >> 6;
  const int wr = (w >> 1) * 64, wc = (w & 1) * 64;   // 4M x 2N waves
  f32x4 acc[4][4] = {};
  for(int t = 0; t < DIM / 64; ++t){
    stage<512, 256>(Aq + t * 64, DIM, As, tid);
    stage<512, 128>(Bk + t * 64, DIM, Bs, tid);
    __syncthreads();
    mma_tile(As, Bs, lane, wr, wc, acc);
    __syncthreads();
  }
  const int cl = lane & 15, rq = (lane >> 4) * 4;
  #pragma unroll
  for(int i = 0; i < 4; ++i){
    const int rbase = wr + i * 16;                    // 0..255
    const int qi = 2 * Qi + (rbase >> 7);
    if(ki > qi) continue;                             // fully-masked half-tile
    const bool diag = (ki == qi);
    __bf16* tile = Pc + ((long)b * NTRI + (long)qi * (qi + 1) / 2 + ki) * 16384;
    float rsum[4] = {0.f, 0.f, 0.f, 0.f};
    #pragma unroll
    for(int j = 0; j < 4; ++j){
      const int c = wc + j * 16 + cl;
      #pragma unroll
      for(int e = 0; e < 4; ++e){
        const int rloc = (rbase + rq + e) & 127;
        float p = (diag && c > rloc) ? 0.0f
                  : __expf(fminf(acc[i][j][e] * SCALE, 30.0f));
        tile[rloc * 128 + c] = (__bf16)p;
        rsum[e] += p;
      }
    }
    #pragma unroll
    for(int e = 0; e < 4; ++e){                       // reduce across 16 col-lanes
      float s = rsum[e];
      s += __shfl_xor(s, 1); s += __shfl_xor(s, 2);
      s += __shfl_xor(s, 4); s += __shfl_xor(s, 8);
      if(cl == 0){
        const long gr = (long)b * SEQ + Qi * 256 + rbase + rq + e;
        atomicAdd(&rlsum[gr], s);
      }
    }
  }
}

// ---------------- P.V: K-split 128x256 GEMM, partials to att0/att1 ----------
__global__ __launch_bounds__(512)
void pv_kernel(const __bf16* __restrict__ Pc, const float* __restrict__ rlsum,
               const __bf16* __restrict__ vbT, __bf16* __restrict__ att0,
               __bf16* __restrict__ att1){
  __shared__ __attribute__((aligned(128))) char As[16384];
  __shared__ __attribute__((aligned(128))) char Bs[32768];
  __shared__ float sRl[128];
  const int x = blockIdx.x, y = blockIdx.y, tid = threadIdx.x;
  const long n0 = (long)(x >> 2) * 256;
  const int b = x & 3;
  int qi, k0, k1, half;
  if(y == 62){ qi = 0; k0 = 0; k1 = 1; half = 0; }
  else{
    qi = 31 - (y >> 1); half = y & 1;
    const int c0 = (qi + 2) >> 1;
    if(half == 0){ k0 = 0; k1 = c0; } else { k0 = c0; k1 = qi + 1; }
  }
  if(tid < 128) sRl[tid] = 1.0f / rlsum[b * SEQ + qi * 128 + tid];
  const __bf16* Pq = Pc + ((long)b * NTRI + (long)qi * (qi + 1) / 2) * 16384;
  const __bf16* Bv = vbT + n0 * TOK + (long)b * SEQ;
  f32x4 acc[4][4] = {};
  auto fa = [&](int t){ return Pq + (long)(k0 + (t >> 1)) * 16384 + (t & 1) * 64; };
  auto fb = [&](int t){ return Bv + (long)k0 * 128 + t * 64; };
  kloop2(fa, 128, fb, TOK, 2 * (k1 - k0), tid, As, Bs, acc);  // barriers cover sRl

  __bf16* dst = half ? att1 : att0;
  const int lane = tid & 63, w = tid >> 6;
  const int wr = (w >> 2) * 64, wc = (w & 3) * 64;
  const int cl = lane & 15, rq = (lane >> 4) * 4;
  #pragma unroll
  for(int i = 0; i < 4; ++i)
    #pragma unroll
    for(int j = 0; j < 4; ++j){
      const long gc = n0 + wc + j * 16 + cl;
      #pragma unroll
      for(int e = 0; e < 4; ++e){
        const int rloc = wr + i * 16 + rq + e;
        float v = acc[i][j][e] * sRl[rloc];
        dst[((long)b * SEQ + qi * 128 + rloc) * DIM + gc] = (__bf16)v;
      }
    }
  if(y == 62){
    // qi=0 rows of att1 are never written by half=1 blocks: zero them here.
    const int r = tid >> 2;
    const int c0 = (tid & 3) * 64;
    __bf16* z0 = att1 + ((long)b * SEQ + r) * DIM + n0 + c0;
    bf16x8 zz = {};
    #pragma unroll
    for(int i = 0; i < 8; ++i) *(bf16x8*)(z0 + i * 8) = zz;
  }
}

// ---------------- output projection: A = att0+att1 (fused add) -> fp32 ----------
__global__ __launch_bounds__(512)
void oproj(const __bf16* __restrict__ att0, const __bf16* __restrict__ att1,
           const __bf16* __restrict__ Wob, const float* __restrict__ bo,
           float* __restrict__ out){
  __shared__ __attribute__((aligned(128))) char As[16384];
  __shared__ __attribute__((aligned(128))) char Bs[32768];
  const int bid = blockIdx.x, tid = threadIdx.x;
  const long n0 = (bid % 3) * 256, m0 = (long)(bid / 3) * 128;
  const __bf16* Br = Wob + n0 * DIM;
  f32x4 acc[4][4] = {};
  const int lane = tid & 63, w = tid >> 6;
  const int wr = (w >> 2) * 64, wc = (w & 3) * 64;
  for(int t = 0; t < DIM / 64; ++t){
    stage_add<512, 128>(att0 + m0 * DIM + t * 64, att1 + m0 * DIM + t * 64, DIM, As, tid);
    stage<512, 256>(Br + t * 64, DIM, Bs, tid);
    __syncthreads();
    mma_tile(As, Bs, lane, wr, wc, acc);
    __syncthreads();
  }
  const int cl = lane & 15, rq = (lane >> 4) * 4;
  #pragma unroll
  for(int i = 0; i < 4; ++i)
    #pragma unroll
    for(int j = 0; j < 4; ++j){
      const long gc = n0 + wc + j * 16 + cl;
      #pragma unroll
      for(int e = 0; e < 4; ++e){
        const long gr = m0 + wr + i * 16 + rq + e;
        out[gr * DIM + gc] = acc[i][j][e] + bo[gc];
      }
    }
}

// ---------------- launch ----------------
extern "C" void kernel_launch(void* const* d_in, const int* in_sizes, int n_in,
                              void* d_out, int out_size, void* d_ws, size_t ws_size,
                              hipStream_t stream){
  const float* query = (const float*)d_in[0];
  const float* key_  = (const float*)d_in[1];
  const float* value = (const float*)d_in[2];
  const float* Wq = (const float*)d_in[3];
  const float* bq = (const float*)d_in[4];
  const float* Wk = (const float*)d_in[5];
  const float* bk = (const float*)d_in[6];
  const float* Wv = (const float*)d_in[7];
  const float* bv = (const float*)d_in[8];
  const float* Wo = (const float*)d_in[9];
  const float* bo = (const float*)d_in[10];
  // d_in[11]: causal tril mask — implemented structurally (block-triangular P).

  char* p = (char*)d_ws;
  auto carve = [&](size_t bytes)->char*{
    char* r = p; p += (bytes + 255) & ~(size_t)255; return r;
  };
  const size_t tb = (size_t)TOK * DIM * 2;   // 25.2 MB
  __bf16* xq  = (__bf16*)carve(tb);
  __bf16* xk  = (__bf16*)carve(tb);
  __bf16* xv  = (__bf16*)carve(tb);
  __bf16* qb  = (__bf16*)carve(tb);
  __bf16* kb  = (__bf16*)carve(tb);
  __bf16* vbT = (__bf16*)carve(tb);
  __bf16* Wqb = (__bf16*)carve((size_t)DIM * DIM * 2);
  __bf16* Wkb = (__bf16*)carve((size_t)DIM * DIM * 2);
  __bf16* Wvb = (__bf16*)carve((size_t)DIM * DIM * 2);
  __bf16* Wob = (__bf16*)carve((size_t)DIM * DIM * 2);
  __bf16* Pc  = (__bf16*)carve((size_t)BATCH * NTRI * 16384 * 2);  // 69.2 MB
  float*  rlr = (float*)carve((size_t)TOK * 4);
  __bf16* att0 = xq;                          // xq, xk dead after proj
  __bf16* att1 = xk;
  if((size_t)(p - (char*)d_ws) > ws_size) return;

  const long nIn4 = TOK * DIM / 4, nW4 = (long)DIM * DIM / 4;
  dim3 g3(2048, 3), g4((unsigned)((nW4 + 255) / 256), 4);
  hipMemsetAsync(rlr, 0, (size_t)TOK * 4, stream);     // row-sum accumulators
  cvt3_kernel<<<g3, 256, 0, stream>>>(query, key_, value, xq, xk, xv, nIn4);
  cvt4_kernel<<<g4, 256, 0, stream>>>(Wq, Wk, Wv, Wo, Wqb, Wkb, Wvb, Wob, nW4);

  // Q, K, V^T projections: 256^2 8-phase all-bf16
  proj_qkv<<<dim3(192, 3), 512, 0, stream>>>(xq, xk, xv, Wqb, Wkb, Wvb,
                                             bq, bk, bv, qb, kb, vbT);

  // QK^T with fused exp + row-sum atomics; XCD-swizzled 1D grid (1088 = 8*136)
  qk_kernel<<<1088, 512, 0, stream>>>(qb, kb, Pc, rlr);

  // P.V with balanced 2-way K-split (756 blocks, longest chunks first)
  pv_kernel<<<dim3(12, 63), 512, 0, stream>>>(Pc, rlr, vbT, att0, att1);

  // output projection, att0+att1 fused into A-staging -> fp32 d_out
  oproj<<<384, 512, 0, stream>>>(att0, att1, Wob, bo, (float*)d_out);
}